// Round 1
// baseline (1336.998 us; speedup 1.0000x reference)
//
#include <hip/hip_runtime.h>
#include <hip/hip_cooperative_groups.h>
#include <stdint.h>

namespace cg = cooperative_groups;

// Problem constants (from reference)
#define ROWS 4096
#define COLS 11008
#define NTOT (ROWS * COLS)          // 45,088,768
#define NV4  (NTOT / 4)             // 11,272,192 (COLS % 4 == 0)
#define COLS4 (COLS / 4)            // 2752

// high_num = int(n*0.1); 1-indexed order-statistic ranks
#define HIGH_NUM 4508876u
#define RANK_LO  (HIGH_NUM / 2u)                   // 2,254,438
#define RANK_HI  ((unsigned)NTOT - HIGH_NUM / 2u)  // 42,834,330

#define BLK 256
#define GRID 2048                    // fallback grid for passA/quant
#define FGRID 1024                   // fused cooperative grid (4 blocks/CU safe)
#define NTILES 11008                 // NV4 / 1024 (tile = 1024 float4)

// Sampling: 1024 blocks x 1024 contiguous float4 = 4,194,304 samples (16 MB)
#define SAMPLES 4194304ull
#define RS_LO ((unsigned)(((unsigned long long)RANK_LO * SAMPLES) / (unsigned long long)NTOT))
#define RS_HI ((unsigned)(((unsigned long long)RANK_HI * SAMPLES) / (unsigned long long)NTOT))
#define M_S 4500u                    // +/-10 sigma sample-rank margin

#define FSPAN (2u << 20)             // coarse window span: 2 x 12-bit buckets (keys)
#define FBINS (1u << 19)             // fine sample hist: 4-key bins over FSPAN
#define WMAX  (1u << 19)             // passA element hist: full-key-res window cap

// ws layout (u32 words), total ~8.4 MB
#define OFF_CLO   0                       // 64 slots: exact #elems key < kA_lo
#define OFF_CHI   64                      // 64 slots: exact #elems key < kA_hi
#define OFF_META  128  // [0]=wstart_lo [1]=wstart_hi [2]=kA_lo [3]=width_lo
                       // [4]=kA_hi [5]=width_hi [6]=Cs_lo [7]=Cs_hi
#define OFF_THR   144                     // 2 floats (exact thresholds)
#define OFF_H1S   256                     // 4096 coarse sample hist
#define OFF_FCS   (OFF_H1S + 4096)        // 1024 fine-sample chunk sums (512/target)
#define OFF_WCS   (OFF_FCS + 1024)        // 1024 passA chunk sums (512/target)
#define OFF_FLO   8192                    // 2^19 fine sample hist (lo)
#define OFF_FHI   (OFF_FLO + FBINS)       // 2^19 fine sample hist (hi)
#define OFF_WLO   (OFF_FHI + FBINS)       // 2^19 passA element hist (lo)
#define OFF_WHI   (OFF_WLO + WMAX)        // 2^19 passA element hist (hi)
#define WS_WORDS  (OFF_WHI + WMAX)

typedef float vfloat4 __attribute__((ext_vector_type(4)));

__device__ __forceinline__ unsigned f2key(float f) {
    unsigned u = __float_as_uint(f);
    return (u & 0x80000000u) ? ~u : (u | 0x80000000u);
}
__device__ __forceinline__ float key2f(unsigned key) {
    unsigned u = (key & 0x80000000u) ? (key & 0x7fffffffu) : ~key;
    return __uint_as_float(u);
}
// Exact qdq (IEEE div + nearest-even) — byte-identical to all passing rounds.
__device__ __forceinline__ float qdq(float xx, bool m, float sl, float zl, float sh, float zh) {
    float s  = m ? sl : sh;
    float z  = m ? zl : zh;
    float mq = m ? 1.0f : 255.0f;
    float q = rintf(xx / s) + z;
    q = fminf(fmaxf(q, 0.0f), mq);
    return s * (q - z);
}
// agent-scope (device-coherent) scalar load — cross-XCD safe after grid.sync
__device__ __forceinline__ unsigned ld_agent(const unsigned* p) {
    return __hip_atomic_load(p, __ATOMIC_RELAXED, __HIP_MEMORY_SCOPE_AGENT);
}

__device__ __forceinline__ void passA_elem(float f, unsigned kAlo, unsigned wLo,
                                           unsigned kAhi, unsigned wHi,
                                           unsigned& cLo, unsigned& cHi,
                                           unsigned* hLo, unsigned* hHi) {
    unsigned key = f2key(f);
    cLo += (key < kAlo) ? 1u : 0u;
    cHi += (key < kAhi) ? 1u : 0u;
    unsigned d0 = key - kAlo;
    if (d0 < wLo) atomicAdd(&hLo[d0], 1u);
    unsigned d1 = key - kAhi;
    if (d1 < wHi) atomicAdd(&hHi[d1], 1u);
}

// ---------- fused-kernel phase helpers (shared smem passed in) ----------
__device__ __forceinline__ void csum_dev(const unsigned* __restrict__ p,
                                         unsigned* __restrict__ dst,
                                         unsigned* __restrict__ red) {
    const int t = threadIdx.x;
    unsigned s = p[t] + p[t + 256] + p[t + 512] + p[t + 768];
    red[t] = s;
    for (int off = 128; off > 0; off >>= 1) {
        __syncthreads();
        if (t < off) red[t] += red[t + off];
    }
    if (t == 0) *dst = red[0];
}

__device__ void fine_scan_dev(unsigned* __restrict__ ws, int tgt,
                              unsigned* __restrict__ smem) {
    unsigned* part = smem;           // [0,256)
    unsigned* sT   = smem + 256;
    unsigned* sC   = smem + 257;
    unsigned* sR   = smem + 258;
    unsigned* sBin = smem + 259;     // [259,261)
    const int t = threadIdx.x;
    const unsigned* cs = ws + OFF_FCS + tgt * 512;
    unsigned c0 = cs[2 * t], c1 = cs[2 * t + 1];
    unsigned gsum = c0 + c1;
    part[t] = gsum;
    __syncthreads();
    for (int off = 1; off < 256; off <<= 1) {
        unsigned a = (t >= off) ? part[t - off] : 0u;
        __syncthreads();
        part[t] += a;
        __syncthreads();
    }
    if (t == 255) *sT = part[255];
    __syncthreads();
    const unsigned T = *sT;
    const unsigned incl = part[t], excl = incl - gsum;   // keep in registers
    unsigned Rs = tgt ? RS_HI : RS_LO;
    unsigned Cs = ld_agent(ws + OFF_META + 6 + tgt);
    unsigned RsA = Rs - Cs;
    if (RsA < 1u) RsA = 1u;
    if (RsA > T) RsA = T;
    unsigned rA = (RsA > M_S) ? RsA - M_S : 1u;
    unsigned rB = RsA + M_S;
    if (rB > T) rB = T;

    for (int q = 0; q < 2; q++) {
        unsigned r = q ? rB : rA;
        if (excl < r && incl >= r) {
            if (excl + c0 >= r) { *sC = 2u * t;      *sR = r - excl; }
            else                { *sC = 2u * t + 1u; *sR = r - excl - c0; }
        }
        __syncthreads();
        unsigned chunk = *sC, rr = *sR;
        __syncthreads();
        const unsigned* hp = ws + OFF_FLO + (size_t)tgt * FBINS + (size_t)chunk * 1024;
        unsigned w[4];
        unsigned s2 = 0u;
#pragma unroll
        for (int i = 0; i < 4; i++) { w[i] = hp[t * 4 + i]; s2 += w[i]; }
        part[t] = s2;
        __syncthreads();
        for (int off = 1; off < 256; off <<= 1) {
            unsigned a = (t >= off) ? part[t - off] : 0u;
            __syncthreads();
            part[t] += a;
            __syncthreads();
        }
        unsigned incl2 = part[t], excl2 = incl2 - s2;
        if (excl2 < rr && incl2 >= rr) {
            unsigned cum = excl2;
            for (int i = 0; i < 4; i++) {
                if (cum + w[i] >= rr) { sBin[q] = chunk * 1024u + (unsigned)(t * 4 + i); break; }
                cum += w[i];
            }
        }
        __syncthreads();
    }
    if (t == 0) {
        unsigned wstart = ld_agent(ws + OFF_META + tgt);
        unsigned kA = wstart + sBin[0] * 4u;
        unsigned kB = wstart + (sBin[1] + 1u) * 4u;
        unsigned width = kB - kA;
        if (width > WMAX) width = WMAX;
        ws[OFF_META + 2 + 2 * tgt] = kA;
        ws[OFF_META + 3 + 2 * tgt] = width;
    }
}

__device__ void scanB_dev(unsigned* __restrict__ ws, int tgt,
                          unsigned* __restrict__ smem) {
    unsigned* part   = smem;
    unsigned* sCtot  = smem + 256;
    unsigned* sChunk = smem + 257;
    unsigned* sRr    = smem + 258;
    const int t = threadIdx.x;
    float* thr = (float*)(ws + OFF_THR);

    part[t] = (t < 64) ? ld_agent(ws + (tgt ? OFF_CHI : OFF_CLO) + t) : 0u;
    for (int off = 128; off > 0; off >>= 1) {
        __syncthreads();
        if (t < off) part[t] += part[t + off];
    }
    if (t == 0) *sCtot = part[0];
    __syncthreads();
    const unsigned RANK = tgt ? RANK_HI : RANK_LO;
    const unsigned R = RANK - *sCtot;    // 1-indexed residual inside window
    __syncthreads();

    const unsigned* cs = ws + OFF_WCS + tgt * 512;
    unsigned c0 = cs[2 * t], c1 = cs[2 * t + 1];
    unsigned gsum = c0 + c1;
    part[t] = gsum;
    __syncthreads();
    for (int off = 1; off < 256; off <<= 1) {
        unsigned a = (t >= off) ? part[t - off] : 0u;
        __syncthreads();
        part[t] += a;
        __syncthreads();
    }
    unsigned incl = part[t], excl = incl - gsum;
    if (excl < R && incl >= R) {
        if (excl + c0 >= R) { *sChunk = 2u * t;      *sRr = R - excl; }
        else                { *sChunk = 2u * t + 1u; *sRr = R - excl - c0; }
    }
    __syncthreads();
    unsigned chunk = *sChunk, rr = *sRr;
    __syncthreads();

    const unsigned* hp = ws + (tgt ? OFF_WHI : OFF_WLO) + (size_t)chunk * 1024;
    unsigned w[4];
    unsigned s2 = 0u;
#pragma unroll
    for (int i = 0; i < 4; i++) { w[i] = hp[t * 4 + i]; s2 += w[i]; }
    part[t] = s2;
    __syncthreads();
    for (int off = 1; off < 256; off <<= 1) {
        unsigned a = (t >= off) ? part[t - off] : 0u;
        __syncthreads();
        part[t] += a;
        __syncthreads();
    }
    unsigned incl2 = part[t], excl2 = incl2 - s2;
    if (excl2 < rr && incl2 >= rr) {
        unsigned cum = excl2;
        for (int i = 0; i < 4; i++) {
            if (cum + w[i] >= rr) {
                unsigned key = ld_agent(ws + OFF_META + 2 + 2 * tgt) + chunk * 1024u + (unsigned)(t * 4 + i);
                thr[tgt] = key2f(key);
                break;
            }
            cum += w[i];
        }
    }
}

// ================= fused cooperative kernel: entire pipeline, 1 dispatch ======
// grid = 1024 blocks x 256 thr; 16 KiB LDS -> >=4 blocks/CU co-resident
// (LDS cap 10/CU, wave cap 8/CU, VGPR cap >=4/CU via __launch_bounds__(256,4)).
__global__ void __launch_bounds__(BLK, 4) fused_kernel(
    const float* __restrict__ x,
    const float* __restrict__ sl_, const float* __restrict__ zl_,
    const float* __restrict__ sh_, const float* __restrict__ zh_,
    unsigned* __restrict__ ws, float* __restrict__ out)
{
    cg::grid_group gg = cg::this_grid();
    __shared__ unsigned smem[4096];       // P1 hist; scan scratch elsewhere
    const unsigned bid = blockIdx.x;
    const int t = threadIdx.x;
    const float4* x4 = (const float4*)x;

    // ---- P0: zero workspace (replaces hipMemsetAsync) ----
    for (unsigned i = bid * BLK + (unsigned)t; i < WS_WORDS; i += FGRID * BLK)
        ws[i] = 0u;
    gg.sync();

    // ---- P1: coarse 12-bit sample histogram (16 MB of x sampled) ----
    {
        for (int i = t; i < 4096; i += BLK) smem[i] = 0u;
        __syncthreads();
        const unsigned base = bid * 11008u;
#pragma unroll
        for (int i = 0; i < 4; i++) {
            float4 v = x4[base + t + 256 * i];
            atomicAdd(&smem[f2key(v.x) >> 20], 1u);
            atomicAdd(&smem[f2key(v.y) >> 20], 1u);
            atomicAdd(&smem[f2key(v.z) >> 20], 1u);
            atomicAdd(&smem[f2key(v.w) >> 20], 1u);
        }
        __syncthreads();
        unsigned* hist = ws + OFF_H1S;
        for (int i = t; i < 4096; i += BLK) {
            unsigned c = smem[i];
            if (c) atomicAdd(&hist[i], c);
        }
    }
    gg.sync();

    // ---- P2: coarse scan -> 2-bucket windows + below-window counts (block 0) ----
    if (bid == 0) {
        unsigned* part = smem;
        const unsigned* hist = ws + OFF_H1S;
        unsigned* meta = ws + OFF_META;
        unsigned v[16];
        unsigned sum = 0u;
#pragma unroll
        for (int i = 0; i < 16; i++) { v[i] = hist[t * 16 + i]; sum += v[i]; }
        part[t] = sum;
        __syncthreads();
        for (int off = 1; off < 256; off <<= 1) {
            unsigned a = (t >= off) ? part[t - off] : 0u;
            __syncthreads();
            part[t] += a;
            __syncthreads();
        }
        unsigned incl = part[t];
        unsigned excl = incl - sum;
        unsigned ranks[2] = {RS_LO, RS_HI};
        for (int k = 0; k < 2; k++) {
            unsigned Rs = ranks[k];
            if (excl < Rs && incl >= Rs) {
                unsigned cum = excl;
                for (int i = 0; i < 16; i++) {
                    if (cum + v[i] >= Rs) {
                        unsigned b = (unsigned)(t * 16 + i);
                        unsigned rel = Rs - cum;
                        unsigned wb = (2u * rel <= v[i]) ? (b > 0 ? b - 1 : 0) : b;
                        if (wb > 4094u) wb = 4094u;
                        meta[k] = wb << 20;                 // window start key
                        unsigned Cs = cum;
                        if (wb < b) Cs -= hist[b - 1];
                        meta[6 + k] = Cs;
                        break;
                    }
                    cum += v[i];
                }
            }
        }
    }
    gg.sync();

    // ---- P3: fine (4-key-bin) sample hist inside coarse windows ----
    {
        const unsigned w0 = __builtin_amdgcn_readfirstlane(ld_agent(ws + OFF_META + 0));
        const unsigned w1 = __builtin_amdgcn_readfirstlane(ld_agent(ws + OFF_META + 1));
        unsigned* f0 = ws + OFF_FLO;
        unsigned* f1 = ws + OFF_FHI;
        const unsigned base = bid * 11008u;
#pragma unroll
        for (int i = 0; i < 4; i++) {
            float4 v = x4[base + t + 256 * i];
            float f[4] = {v.x, v.y, v.z, v.w};
#pragma unroll
            for (int c = 0; c < 4; c++) {
                unsigned key = f2key(f[c]);
                unsigned d0 = key - w0;
                if (d0 < FSPAN) atomicAdd(&f0[d0 >> 2], 1u);
                unsigned d1 = key - w1;
                if (d1 < FSPAN) atomicAdd(&f1[d1 >> 2], 1u);
            }
        }
    }
    gg.sync();

    // ---- P4: chunk sums over FLO+FHI (contiguous 2^20 words, 1 chunk/block) --
    csum_dev(ws + OFF_FLO + (size_t)bid * 1024u, ws + OFF_FCS + bid, smem);
    gg.sync();

    // ---- P5: fine scan -> key cut-points (blocks 0,1) ----
    if (bid < 2) fine_scan_dev(ws, (int)bid, smem);
    gg.sync();

    // ---- P6: passA — exact below-kA counts + narrow-window element hist ----
    {
        const unsigned kAlo = __builtin_amdgcn_readfirstlane(ld_agent(ws + OFF_META + 2));
        const unsigned wLo  = __builtin_amdgcn_readfirstlane(ld_agent(ws + OFF_META + 3));
        const unsigned kAhi = __builtin_amdgcn_readfirstlane(ld_agent(ws + OFF_META + 4));
        const unsigned wHi  = __builtin_amdgcn_readfirstlane(ld_agent(ws + OFF_META + 5));
        unsigned* hLo = ws + OFF_WLO;
        unsigned* hHi = ws + OFF_WHI;
        unsigned cLo = 0u, cHi = 0u;

        for (unsigned tile = bid; tile < NTILES; tile += FGRID) {
            const float4* p = x4 + (size_t)tile * 1024u + (unsigned)t;
            float4 a = p[0];
            float4 b = p[256];
            float4 c = p[512];
            float4 d = p[768];
            passA_elem(a.x, kAlo, wLo, kAhi, wHi, cLo, cHi, hLo, hHi);
            passA_elem(a.y, kAlo, wLo, kAhi, wHi, cLo, cHi, hLo, hHi);
            passA_elem(a.z, kAlo, wLo, kAhi, wHi, cLo, cHi, hLo, hHi);
            passA_elem(a.w, kAlo, wLo, kAhi, wHi, cLo, cHi, hLo, hHi);
            passA_elem(b.x, kAlo, wLo, kAhi, wHi, cLo, cHi, hLo, hHi);
            passA_elem(b.y, kAlo, wLo, kAhi, wHi, cLo, cHi, hLo, hHi);
            passA_elem(b.z, kAlo, wLo, kAhi, wHi, cLo, cHi, hLo, hHi);
            passA_elem(b.w, kAlo, wLo, kAhi, wHi, cLo, cHi, hLo, hHi);
            passA_elem(c.x, kAlo, wLo, kAhi, wHi, cLo, cHi, hLo, hHi);
            passA_elem(c.y, kAlo, wLo, kAhi, wHi, cLo, cHi, hLo, hHi);
            passA_elem(c.z, kAlo, wLo, kAhi, wHi, cLo, cHi, hLo, hHi);
            passA_elem(c.w, kAlo, wLo, kAhi, wHi, cLo, cHi, hLo, hHi);
            passA_elem(d.x, kAlo, wLo, kAhi, wHi, cLo, cHi, hLo, hHi);
            passA_elem(d.y, kAlo, wLo, kAhi, wHi, cLo, cHi, hLo, hHi);
            passA_elem(d.z, kAlo, wLo, kAhi, wHi, cLo, cHi, hLo, hHi);
            passA_elem(d.w, kAlo, wLo, kAhi, wHi, cLo, cHi, hLo, hHi);
        }

        unsigned* red = smem;
        red[t] = cLo;
        for (int off = 128; off > 0; off >>= 1) {
            __syncthreads();
            if (t < off) red[t] += red[t + off];
        }
        if (t == 0) atomicAdd(&ws[OFF_CLO + (bid & 63)], red[0]);
        __syncthreads();
        red[t] = cHi;
        for (int off = 128; off > 0; off >>= 1) {
            __syncthreads();
            if (t < off) red[t] += red[t + off];
        }
        if (t == 0) atomicAdd(&ws[OFF_CHI + (bid & 63)], red[0]);
    }
    gg.sync();

    // ---- P7: chunk sums over WLO+WHI ----
    csum_dev(ws + OFF_WLO + (size_t)bid * 1024u, ws + OFF_WCS + bid, smem);
    gg.sync();

    // ---- P8: exact rank select -> thresholds (blocks 0,1) ----
    if (bid < 2) scanB_dev(ws, (int)bid, smem);
    gg.sync();

    // ---- P9: quant — streaming dual qdq, 4x ILP, NT stores ----
    {
        const float lowT  = __uint_as_float(__builtin_amdgcn_readfirstlane(ld_agent(ws + OFF_THR + 0)));
        const float highT = __uint_as_float(__builtin_amdgcn_readfirstlane(ld_agent(ws + OFF_THR + 1)));
        vfloat4* o4 = (vfloat4*)out;

        for (unsigned tile = bid; tile < NTILES; tile += FGRID) {
            const size_t base = (size_t)tile * 1024u + (unsigned)t;
            float4 vv[4];
            vv[0] = x4[base];
            vv[1] = x4[base + 256];
            vv[2] = x4[base + 512];
            vv[3] = x4[base + 768];
#pragma unroll
            for (int u = 0; u < 4; u++) {
                unsigned j = (unsigned)(base + 256u * u);
                unsigned row = j / COLS4;
                float sl = sl_[row], zl = zl_[row];
                float sh = sh_[row], zh = zh_[row];
                float in[4] = {vv[u].x, vv[u].y, vv[u].z, vv[u].w};
                float r[4];
#pragma unroll
                for (int c2 = 0; c2 < 4; c2++) {
                    float xx = in[c2];
                    bool m = (xx > lowT) && (xx < highT);
                    r[c2] = qdq(xx, m, sl, zl, sh, zh);
                }
                vfloat4 rv = {r[0], r[1], r[2], r[3]};
                __builtin_nontemporal_store(rv, &o4[j]);
            }
        }
    }
}

// ================= proven 10-dispatch fallback pipeline =======================
__global__ void __launch_bounds__(BLK) sample_kernel(const float* __restrict__ x,
                                                     unsigned* __restrict__ ws) {
    __shared__ unsigned h[8192];
    for (int i = threadIdx.x; i < 8192; i += BLK) h[i] = 0u;
    __syncthreads();
    const float4* x4 = (const float4*)x;
    const unsigned base = blockIdx.x * 11008u;
    const int par = threadIdx.x & 1;
#pragma unroll
    for (int i = 0; i < 4; i++) {
        float4 v = x4[base + threadIdx.x + 256 * i];
        atomicAdd(&h[((f2key(v.x) >> 20) << 1) + par], 1u);
        atomicAdd(&h[((f2key(v.y) >> 20) << 1) + par], 1u);
        atomicAdd(&h[((f2key(v.z) >> 20) << 1) + par], 1u);
        atomicAdd(&h[((f2key(v.w) >> 20) << 1) + par], 1u);
    }
    __syncthreads();
    unsigned* hist = ws + OFF_H1S;
    for (int i = threadIdx.x; i < 4096; i += BLK) {
        unsigned c = h[2 * i] + h[2 * i + 1];
        if (c) atomicAdd(&hist[i], c);
    }
}

__global__ void __launch_bounds__(BLK) scan_sample_kernel(unsigned* __restrict__ ws) {
    __shared__ unsigned part[256];
    const unsigned* hist = ws + OFF_H1S;
    unsigned* meta = ws + OFF_META;
    int t = threadIdx.x;
    unsigned v[16];
    unsigned sum = 0u;
#pragma unroll
    for (int i = 0; i < 16; i++) { v[i] = hist[t * 16 + i]; sum += v[i]; }
    part[t] = sum;
    __syncthreads();
    for (int off = 1; off < 256; off <<= 1) {
        unsigned a = (t >= off) ? part[t - off] : 0u;
        __syncthreads();
        part[t] += a;
        __syncthreads();
    }
    unsigned incl = part[t];
    unsigned excl = incl - sum;
    unsigned ranks[2] = {RS_LO, RS_HI};
    for (int k = 0; k < 2; k++) {
        unsigned Rs = ranks[k];
        if (excl < Rs && incl >= Rs) {
            unsigned cum = excl;
            for (int i = 0; i < 16; i++) {
                if (cum + v[i] >= Rs) {
                    unsigned b = (unsigned)(t * 16 + i);
                    unsigned rel = Rs - cum;
                    unsigned wb = (2u * rel <= v[i]) ? (b > 0 ? b - 1 : 0) : b;
                    if (wb > 4094u) wb = 4094u;
                    meta[k] = wb << 20;
                    unsigned Cs = cum;
                    if (wb < b) Cs -= hist[b - 1];
                    meta[6 + k] = Cs;
                    break;
                }
                cum += v[i];
            }
        }
    }
}

__global__ void __launch_bounds__(BLK) sample_fine_kernel(const float* __restrict__ x,
                                                          unsigned* __restrict__ ws) {
    const unsigned w0 = __builtin_amdgcn_readfirstlane(ws[OFF_META + 0]);
    const unsigned w1 = __builtin_amdgcn_readfirstlane(ws[OFF_META + 1]);
    unsigned* f0 = ws + OFF_FLO;
    unsigned* f1 = ws + OFF_FHI;
    const float4* x4 = (const float4*)x;
    const unsigned base = blockIdx.x * 11008u;
#pragma unroll
    for (int i = 0; i < 4; i++) {
        float4 v = x4[base + threadIdx.x + 256 * i];
        float f[4] = {v.x, v.y, v.z, v.w};
#pragma unroll
        for (int c = 0; c < 4; c++) {
            unsigned key = f2key(f[c]);
            unsigned d0 = key - w0;
            if (d0 < FSPAN) atomicAdd(&f0[d0 >> 2], 1u);
            unsigned d1 = key - w1;
            if (d1 < FSPAN) atomicAdd(&f1[d1 >> 2], 1u);
        }
    }
}

__global__ void __launch_bounds__(BLK) csum_kernel(const unsigned* __restrict__ src,
                                                   unsigned* __restrict__ dst) {
    const unsigned* p = src + (size_t)blockIdx.x * 1024;
    int t = threadIdx.x;
    unsigned s = p[t] + p[t + 256] + p[t + 512] + p[t + 768];
    __shared__ unsigned red[256];
    red[t] = s;
    for (int off = 128; off > 0; off >>= 1) {
        __syncthreads();
        if (t < off) red[t] += red[t + off];
    }
    if (t == 0) dst[blockIdx.x] = red[0];
}

__global__ void __launch_bounds__(BLK) fine_scan_kernel(unsigned* __restrict__ ws) {
    __shared__ unsigned smem[512];
    fine_scan_dev(ws, blockIdx.x, smem);
}

__global__ void __launch_bounds__(BLK) passA_kernel(const float* __restrict__ x,
                                                    unsigned* __restrict__ ws) {
    const unsigned kAlo = __builtin_amdgcn_readfirstlane(ws[OFF_META + 2]);
    const unsigned wLo  = __builtin_amdgcn_readfirstlane(ws[OFF_META + 3]);
    const unsigned kAhi = __builtin_amdgcn_readfirstlane(ws[OFF_META + 4]);
    const unsigned wHi  = __builtin_amdgcn_readfirstlane(ws[OFF_META + 5]);
    unsigned* hLo = ws + OFF_WLO;
    unsigned* hHi = ws + OFF_WHI;

    const float4* x4 = (const float4*)x;
    unsigned cLo = 0u, cHi = 0u;

    for (unsigned tile = blockIdx.x; tile < NTILES; tile += gridDim.x) {
        const float4* p = x4 + (size_t)tile * 1024u + threadIdx.x;
        float4 a = p[0];
        float4 b = p[256];
        float4 c = p[512];
        float4 d = p[768];
        passA_elem(a.x, kAlo, wLo, kAhi, wHi, cLo, cHi, hLo, hHi);
        passA_elem(a.y, kAlo, wLo, kAhi, wHi, cLo, cHi, hLo, hHi);
        passA_elem(a.z, kAlo, wLo, kAhi, wHi, cLo, cHi, hLo, hHi);
        passA_elem(a.w, kAlo, wLo, kAhi, wHi, cLo, cHi, hLo, hHi);
        passA_elem(b.x, kAlo, wLo, kAhi, wHi, cLo, cHi, hLo, hHi);
        passA_elem(b.y, kAlo, wLo, kAhi, wHi, cLo, cHi, hLo, hHi);
        passA_elem(b.z, kAlo, wLo, kAhi, wHi, cLo, cHi, hLo, hHi);
        passA_elem(b.w, kAlo, wLo, kAhi, wHi, cLo, cHi, hLo, hHi);
        passA_elem(c.x, kAlo, wLo, kAhi, wHi, cLo, cHi, hLo, hHi);
        passA_elem(c.y, kAlo, wLo, kAhi, wHi, cLo, cHi, hLo, hHi);
        passA_elem(c.z, kAlo, wLo, kAhi, wHi, cLo, cHi, hLo, hHi);
        passA_elem(c.w, kAlo, wLo, kAhi, wHi, cLo, cHi, hLo, hHi);
        passA_elem(d.x, kAlo, wLo, kAhi, wHi, cLo, cHi, hLo, hHi);
        passA_elem(d.y, kAlo, wLo, kAhi, wHi, cLo, cHi, hLo, hHi);
        passA_elem(d.z, kAlo, wLo, kAhi, wHi, cLo, cHi, hLo, hHi);
        passA_elem(d.w, kAlo, wLo, kAhi, wHi, cLo, cHi, hLo, hHi);
    }

    __shared__ unsigned red[256];
    red[threadIdx.x] = cLo;
    for (int off = 128; off > 0; off >>= 1) {
        __syncthreads();
        if (threadIdx.x < off) red[threadIdx.x] += red[threadIdx.x + off];
    }
    if (threadIdx.x == 0) atomicAdd(&ws[OFF_CLO + (blockIdx.x & 63)], red[0]);
    __syncthreads();
    red[threadIdx.x] = cHi;
    for (int off = 128; off > 0; off >>= 1) {
        __syncthreads();
        if (threadIdx.x < off) red[threadIdx.x] += red[threadIdx.x + off];
    }
    if (threadIdx.x == 0) atomicAdd(&ws[OFF_CHI + (blockIdx.x & 63)], red[0]);
}

__global__ void __launch_bounds__(BLK) scanB_kernel(unsigned* __restrict__ ws) {
    __shared__ unsigned smem[512];
    scanB_dev(ws, blockIdx.x, smem);
}

__global__ void __launch_bounds__(BLK) quant_kernel(const float* __restrict__ x,
                                                    const float* __restrict__ sl_,
                                                    const float* __restrict__ zl_,
                                                    const float* __restrict__ sh_,
                                                    const float* __restrict__ zh_,
                                                    const unsigned* __restrict__ ws,
                                                    float* __restrict__ out) {
    const float lowT  = __uint_as_float(__builtin_amdgcn_readfirstlane(ws[OFF_THR + 0]));
    const float highT = __uint_as_float(__builtin_amdgcn_readfirstlane(ws[OFF_THR + 1]));
    const float4* x4 = (const float4*)x;
    vfloat4* o4 = (vfloat4*)out;

    for (unsigned tile = blockIdx.x; tile < NTILES; tile += gridDim.x) {
        const size_t base = (size_t)tile * 1024u + threadIdx.x;
        float4 vv[4];
        vv[0] = x4[base];
        vv[1] = x4[base + 256];
        vv[2] = x4[base + 512];
        vv[3] = x4[base + 768];
#pragma unroll
        for (int u = 0; u < 4; u++) {
            unsigned j = (unsigned)(base + 256u * u);
            unsigned row = j / COLS4;
            float sl = sl_[row], zl = zl_[row];
            float sh = sh_[row], zh = zh_[row];
            float in[4] = {vv[u].x, vv[u].y, vv[u].z, vv[u].w};
            float r[4];
#pragma unroll
            for (int c = 0; c < 4; c++) {
                float xx = in[c];
                bool m = (xx > lowT) && (xx < highT);
                r[c] = qdq(xx, m, sl, zl, sh, zh);
            }
            vfloat4 rv = {r[0], r[1], r[2], r[3]};
            __builtin_nontemporal_store(rv, &o4[j]);
        }
    }
}

extern "C" void kernel_launch(void* const* d_in, const int* in_sizes, int n_in,
                              void* d_out, int out_size, void* d_ws, size_t ws_size,
                              hipStream_t stream) {
    const float* x  = (const float*)d_in[0];
    const float* sl = (const float*)d_in[1];
    const float* zl = (const float*)d_in[2];
    const float* sh = (const float*)d_in[3];
    const float* zh = (const float*)d_in[4];
    float* out = (float*)d_out;
    unsigned* ws = (unsigned*)d_ws;

    void* args[] = {(void*)&x, (void*)&sl, (void*)&zl, (void*)&sh, (void*)&zh,
                    (void*)&ws, (void*)&out};
    hipError_t err = hipLaunchCooperativeKernel((void*)fused_kernel, dim3(FGRID), dim3(BLK),
                                                args, 0, stream);
    if (err != hipSuccess) {
        // Fallback: proven 10-dispatch pipeline (391.9 us reference behavior).
        (void)hipMemsetAsync(d_ws, 0, (size_t)WS_WORDS * 4, stream);
        sample_kernel<<<1024, BLK, 0, stream>>>(x, ws);
        scan_sample_kernel<<<1, BLK, 0, stream>>>(ws);
        sample_fine_kernel<<<1024, BLK, 0, stream>>>(x, ws);
        csum_kernel<<<1024, BLK, 0, stream>>>(ws + OFF_FLO, ws + OFF_FCS);
        fine_scan_kernel<<<2, BLK, 0, stream>>>(ws);
        passA_kernel<<<GRID, BLK, 0, stream>>>(x, ws);
        csum_kernel<<<1024, BLK, 0, stream>>>(ws + OFF_WLO, ws + OFF_WCS);
        scanB_kernel<<<2, BLK, 0, stream>>>(ws);
        quant_kernel<<<GRID, BLK, 0, stream>>>(x, sl, zl, sh, zh, ws, out);
    }
}